// Round 1
// baseline (452.915 us; speedup 1.0000x reference)
//
#include <hip/hip_runtime.h>

// Undecimated starlet analysis, 4 scales, separable [1,4,6,4,1]/16 filter,
// dilation 2^s, symmetric boundary. Per-scale fused tile kernel:
// load (TILE+4d)^2 region -> LDS, horizontal pass -> LDS tmp, vertical pass
// + (low - new_low)*inv_norm -> out, new_low -> ws (ping-pong).

#define IMG_H 1024
#define IMG_W 1024
#define NBATCH 16
#define TILE 64

__device__ __forceinline__ int mirror_idx(int g, int n) {
    // jnp.pad mode='symmetric': -1 -> 0, -2 -> 1, n -> n-1, n+1 -> n-2
    g = (g < 0) ? (-1 - g) : g;
    g = (g >= n) ? (2 * n - 1 - g) : g;
    return g;
}

template <int DIL>
__global__ __launch_bounds__(256)
void starlet_scale_kernel(const float* __restrict__ low_in,
                          const float* __restrict__ norms,
                          float* __restrict__ coeff_out,
                          float* __restrict__ low_out,
                          int scale)
{
    constexpr int R  = 2 * DIL;          // filter radius after dilation
    constexpr int R2 = TILE + 2 * R;     // staged region side
    __shared__ float lowbuf[R2 * R2];
    __shared__ float tmp[R2 * TILE];     // rows: R2, cols: TILE

    const int tid = threadIdx.x;
    const int tx0 = blockIdx.x * TILE;
    const int ty0 = blockIdx.y * TILE;
    const size_t img_off = (size_t)blockIdx.z * (size_t)(IMG_H * IMG_W);
    const float inv = 1.0f / norms[scale];

    // ---- stage region with symmetric mirroring (coalesced in rx) ----
    for (int i = tid; i < R2 * R2; i += 256) {
        const int ry = i / R2;
        const int rx = i - ry * R2;
        const int gy = mirror_idx(ty0 - R + ry, IMG_H);
        const int gx = mirror_idx(tx0 - R + rx, IMG_W);
        lowbuf[i] = low_in[img_off + (size_t)gy * IMG_W + gx];
    }
    __syncthreads();

    // ---- horizontal 5-tap dilated pass: tmp[y][x], y in [0,R2), x in [0,TILE) ----
    for (int i = tid; i < R2 * TILE; i += 256) {
        const int y = i >> 6;            // TILE == 64
        const int x = i & (TILE - 1);
        const float* row = &lowbuf[y * R2 + x + R];
        tmp[i] = 0.375f  * row[0]
               + 0.25f   * (row[-DIL]     + row[DIL])
               + 0.0625f * (row[-2 * DIL] + row[2 * DIL]);
    }
    __syncthreads();

    // ---- vertical pass + subtract + normalize + store ----
    for (int i = tid; i < TILE * TILE; i += 256) {
        const int y = i >> 6;
        const int x = i & (TILE - 1);
        const float* col = &tmp[(y + R) * TILE + x];
        const float nl = 0.375f  * col[0]
                       + 0.25f   * (col[-DIL * TILE]     + col[DIL * TILE])
                       + 0.0625f * (col[-2 * DIL * TILE] + col[2 * DIL * TILE]);
        const float lo = lowbuf[(y + R) * R2 + (x + R)];
        const size_t go = img_off + (size_t)(ty0 + y) * IMG_W + (tx0 + x);
        coeff_out[go] = (lo - nl) * inv;
        if (low_out) low_out[go] = nl;
    }
}

extern "C" void kernel_launch(void* const* d_in, const int* in_sizes, int n_in,
                              void* d_out, int out_size, void* d_ws, size_t ws_size,
                              hipStream_t stream) {
    const float* image = (const float*)d_in[0];
    const float* norms = (const float*)d_in[1];
    float* out = (float*)d_out;

    const size_t plane = (size_t)NBATCH * IMG_H * IMG_W;  // 16M floats = 64 MB
    float* wsA = (float*)d_ws;
    float* wsB = wsA + plane;                             // needs 128 MB of ws

    dim3 grid(IMG_W / TILE, IMG_H / TILE, NBATCH);
    dim3 block(256);

    starlet_scale_kernel<1><<<grid, block, 0, stream>>>(image, norms, out,             wsA,     0);
    starlet_scale_kernel<2><<<grid, block, 0, stream>>>(wsA,   norms, out + plane,     wsB,     1);
    starlet_scale_kernel<4><<<grid, block, 0, stream>>>(wsB,   norms, out + 2 * plane, wsA,     2);
    starlet_scale_kernel<8><<<grid, block, 0, stream>>>(wsA,   norms, out + 3 * plane, nullptr, 3);
}